// Round 13
// baseline (1237.630 us; speedup 1.0000x reference)
//
#include <hip/hip_runtime.h>
#include <stdint.h>

#define T_LEN 512
#define BATCH 32
#define NIN   72
#define NOUT  90
#define HDIM  512
#define MROWS (T_LEN*BATCH)   // 16384

typedef unsigned short u16;
typedef unsigned int   u32;

typedef __bf16 bf16x8 __attribute__((ext_vector_type(8)));
typedef short  s16x8  __attribute__((ext_vector_type(8)));
typedef float  f32x4  __attribute__((ext_vector_type(4)));

__device__ __forceinline__ float b2f(u16 u){ return __uint_as_float(((u32)u)<<16); }
__device__ __forceinline__ u16 f2b(float x){
  u32 u = __float_as_uint(x);
  u += 0x7FFFu + ((u>>16)&1u);          // RNE
  return (u16)(u>>16);
}
__device__ __forceinline__ float sigmoidf_(float z){ return 1.f/(1.f+__expf(-z)); }
__device__ __forceinline__ float tanhf_(float z){ return 2.f/(1.f+__expf(-2.f*z)) - 1.f; }

__device__ __forceinline__ void gload16(const void* g, void* l){
  __builtin_amdgcn_global_load_lds(
      (const __attribute__((address_space(1))) void*)g,
      (__attribute__((address_space(3))) void*)l, 16, 0, 0);
}

// ---------------- transpose + cast: (K,N) f32 -> (N,K) bf16 ----------------
__global__ __launch_bounds__(256) void k_transpose_cast(
    const float* __restrict__ S, u16* __restrict__ D, int K, int N, int ldd)
{
  __shared__ float t[32][33];
  int k0 = blockIdx.y*32, n0 = blockIdx.x*32;
  int tx = threadIdx.x, ty = threadIdx.y;   // 32 x 8
  #pragma unroll
  for (int i=0;i<4;++i){
    int k = k0 + ty + i*8, n = n0 + tx;
    if (k < K && n < N) t[ty+i*8][tx] = S[(size_t)k*N + n];
  }
  __syncthreads();
  #pragma unroll
  for (int i=0;i<4;++i){
    int n = n0 + ty + i*8, k = k0 + tx;
    if (n < N && k < K) D[(size_t)n*ldd + k] = f2b(t[tx][ty+i*8]);
  }
}

// ---------------- input projection: relu(x@W1+b1) -> bf16 ----------------
__global__ __launch_bounds__(256) void k_gemm1_relu(
    const float* __restrict__ X, const float* __restrict__ W1,
    const float* __restrict__ b1, u16* __restrict__ H0)
{
  __shared__ float As[64][73];
  __shared__ float Bs[72][64];
  int m0 = blockIdx.y*64, n0 = blockIdx.x*64;
  int tid = threadIdx.x;
  for (int idx=tid; idx<64*NIN; idx+=256){ int r=idx/NIN, k=idx-r*NIN; As[r][k] = X[(size_t)(m0+r)*NIN + k]; }
  for (int idx=tid; idx<NIN*64; idx+=256){ int k=idx>>6, n=idx&63; Bs[k][n] = W1[(size_t)k*HDIM + n0+n]; }
  __syncthreads();
  int tx = tid & 15, ty = tid >> 4;
  float acc[4][4] = {};
  for (int k=0;k<NIN;++k){
    float a[4], bv[4];
    #pragma unroll
    for (int i=0;i<4;++i) a[i]=As[ty*4+i][k];
    #pragma unroll
    for (int j=0;j<4;++j) bv[j]=Bs[k][tx*4+j];
    #pragma unroll
    for (int i=0;i<4;++i)
      #pragma unroll
      for (int j=0;j<4;++j) acc[i][j] += a[i]*bv[j];
  }
  #pragma unroll
  for (int i=0;i<4;++i){
    int row = m0 + ty*4 + i;
    #pragma unroll
    for (int j=0;j<4;++j){
      int col = n0 + tx*4 + j;
      float v = acc[i][j] + b1[col];
      H0[(size_t)row*HDIM + col] = f2b(v > 0.f ? v : 0.f);
    }
  }
}

// ---------------- LayerNorm (bf16 in -> bf16 out), one wave per row ----------------
template<int D>
__global__ __launch_bounds__(256) void k_ln(
    const u16* __restrict__ X, const float* __restrict__ g,
    const float* __restrict__ be, u16* __restrict__ Y)
{
  int wrow = (blockIdx.x*256 + threadIdx.x) >> 6;
  int lane = threadIdx.x & 63;
  constexpr int E = D/64;
  const u16* row = X + (size_t)wrow*D;
  float vals[E];
  float s=0.f, s2=0.f;
  #pragma unroll
  for (int i=0;i<E/4;++i){
    ushort4 u = *(const ushort4*)(row + i*256 + lane*4);
    float v0=b2f(u.x), v1=b2f(u.y), v2=b2f(u.z), v3=b2f(u.w);
    vals[i*4+0]=v0; vals[i*4+1]=v1; vals[i*4+2]=v2; vals[i*4+3]=v3;
    s  += v0+v1+v2+v3;
    s2 += v0*v0+v1*v1+v2*v2+v3*v3;
  }
  #pragma unroll
  for (int off=32; off; off>>=1){ s += __shfl_xor(s,off); s2 += __shfl_xor(s2,off); }
  float mean = s * (1.f/D);
  float var  = s2 * (1.f/D) - mean*mean;
  float rstd = rsqrtf(var + 1e-5f);
  u16* yr = Y + (size_t)wrow*D;
  #pragma unroll
  for (int i=0;i<E/4;++i){
    int col = i*256 + lane*4;
    float4 gg = *(const float4*)(g+col);
    float4 bb = *(const float4*)(be+col);
    ushort4 o;
    o.x = f2b((vals[i*4+0]-mean)*rstd*gg.x + bb.x);
    o.y = f2b((vals[i*4+1]-mean)*rstd*gg.y + bb.y);
    o.z = f2b((vals[i*4+2]-mean)*rstd*gg.z + bb.z);
    o.w = f2b((vals[i*4+3]-mean)*rstd*gg.w + bb.w);
    *(ushort4*)(yr + col) = o;
  }
}

// ======== 256x256 bf16 MFMA GEMM v5: 16 waves x 64x64 acc, BK=32, <=128 regs ===
// Theory: R7-R12 kernel used 256 unified regs/wave (acc 128 AGPR + 128 VGPR) ->
// 8 waves/CU = 2 waves/SIMD -> every schedule stall exposed (no other wave to
// run).  v5: 1024 threads = 16 waves (4Mx4N), per-wave C = 64x64 (acc[4][4] =
// 64 regs), BK=32, LDS 64KB -> target <=128 regs/wave = 16 waves/CU = 4
// waves/SIMD: SIMD-level interleave hides ds_read/MFMA/barrier bubbles (m114).
// Swizzle for 64B-row tiles: granule' = granule ^ ((granule>>3)&7) — involution
// (key bits 3-5 unmodified); frag read touches 64 DISTINCT granules per wave
// (conflict-free); staging uses the same involution on the global source with
// linear LDS dest (rule #21: both-sides-or-neither).
// Schedule per tile: ONE barrier + ONE vmcnt(0) + 4 lgkm, reads one quadrant
// ahead, setprio around MFMA (R7 skeleton, thinner quadrants).
__global__ __launch_bounds__(1024, 1) void k_gemm256(
    const u16* __restrict__ A, const u16* __restrict__ BT,
    u16* __restrict__ C, int K, int N)
{
  __shared__ u16 lds[32768];   // 64 KiB: 2 x (A 16KB + B 16KB)
  const int tid  = threadIdx.x;
  const int lane = tid & 63;
  const int wid  = tid >> 6;        // 0..15
  const int wm   = wid >> 2;        // 0..3 (64-row band)
  const int wn   = wid & 3;         // 0..3 (64-col band)

  // XCD-aware bijective swizzle (nwg % 8 == 0 for all launches)
  const int nbx = gridDim.x;
  const int nwg = nbx * gridDim.y;
  const int bid = blockIdx.y * nbx + blockIdx.x;
  const int cpx = nwg >> 3;
  const int swz = (bid & 7) * cpx + (bid >> 3);
  const int m0 = (swz / nbx) * 256;
  const int n0 = (swz % nbx) * 256;

  // staging: physical granule = lane; logical = lane ^ ((lane>>3)&7)
  const int glog = lane ^ ((lane >> 3) & 7);
  const int srow = glog >> 2;       // 0..15 row within 16-row segment
  const int sq   = glog & 3;        // 8-elem chunk within 32-elem row

  auto stageA = [&](int ts, int db){
    gload16(A + (size_t)(m0 + wid*16 + srow)*K + ts*32 + sq*8,
            lds + db*16384 + wid*512);
  };
  auto stageB = [&](int ts, int db){
    gload16(BT + (size_t)(n0 + wid*16 + srow)*K + ts*32 + sq*8,
            lds + db*16384 + 8192 + wid*512);
  };
  // swizzled fragment read: row in [0,256); lane reads 16B at k-chunk lane>>4
  auto rdfrag = [&](const u16* buf, int row)->bf16x8 {
    int gr = row*4 + (lane>>4);
    gr ^= (gr>>3)&7;
    return __builtin_bit_cast(bf16x8, *(const s16x8*)((const char*)buf + gr*16));
  };

  f32x4 acc[4][4] = {};
  bf16x8 afr[2];       // A frag, parity by quadrant
  bf16x8 bfr[4];       // B frags for current tile
  const int nt = K >> 5;   // 16 (K=512) or 32 (K=1024)

  // prologue: stage tile 0, drain, read B(0)+A0(0)
  stageA(0, 0);
  stageB(0, 0);
  asm volatile("s_waitcnt vmcnt(0)" ::: "memory");
  __builtin_amdgcn_sched_barrier(0);
  __builtin_amdgcn_s_barrier();
  __builtin_amdgcn_sched_barrier(0);
  #pragma unroll
  for (int n=0;n<4;++n)
    bfr[n] = rdfrag(lds + 8192, wn*64 + n*16 + (lane&15));
  afr[0] = rdfrag(lds, wm*64 + (lane&15));

  for (int t = 0; t < nt; ++t){
    const u16* bufA = lds + (t & 1)*16384;
    const int  tn   = (t+1 < nt) ? t+1 : t;   // tail: dummy re-stage keeps counts uniform
    const int  db   = (t+1) & 1;
    const u16* bufAn = lds + db*16384;
    const u16* bufBn = bufAn + 8192;

    // TOP: stage tile t+1 (2 vmem ops)
    stageA(tn, db);
    stageB(tn, db);

    // quadrants: q handles m-frag q (rows wm*64 + q*16 + lane&15)
    #pragma unroll
    for (int q=0;q<4;++q){
      asm volatile("s_waitcnt lgkmcnt(0)" ::: "memory");   // this quadrant's frags ready
      __builtin_amdgcn_sched_barrier(0);
      if (q < 3)
        afr[(q+1)&1] = rdfrag(bufA, wm*64 + (q+1)*16 + (lane&15));
      __builtin_amdgcn_sched_barrier(0);   // pin read-issue BEFORE the MFMA cluster
      __builtin_amdgcn_s_setprio(1);
      #pragma unroll
      for (int n=0;n<4;++n)
        acc[q][n] = __builtin_amdgcn_mfma_f32_16x16x32_bf16(
            afr[q&1], bfr[n], acc[q][n], 0,0,0);
      __builtin_amdgcn_s_setprio(0);
    }

    // drain staging (issued ~4 quadrants ago), barrier, read next tile's frags
    asm volatile("s_waitcnt vmcnt(0)" ::: "memory");
    __builtin_amdgcn_sched_barrier(0);
    __builtin_amdgcn_s_barrier();
    __builtin_amdgcn_sched_barrier(0);
    #pragma unroll
    for (int n=0;n<4;++n)
      bfr[n] = rdfrag(bufBn, wn*64 + n*16 + (lane&15));
    afr[0] = rdfrag(bufAn, wm*64 + (lane&15));
  }

  // epilogue: C write (bf16)
  #pragma unroll
  for (int m=0;m<4;++m){
    int row = m0 + wm*64 + m*16 + ((lane>>4)<<2);
    #pragma unroll
    for (int n=0;n<4;++n){
      int col = n0 + wn*64 + n*16 + (lane&15);
      #pragma unroll
      for (int i=0;i<4;++i)
        C[(size_t)(row+i)*N + col] = f2b(acc[m][n][i]);
    }
  }
}

// ---------------- old 128x128 GEMM (kept for the small out-projection) ----------------
template<bool OUT_F32, bool HAS_BIAS>
__global__ __launch_bounds__(256) void k_gemm(
    const u16* __restrict__ A, const u16* __restrict__ BT,
    void* __restrict__ Cv, const float* __restrict__ bias,
    int K, int N, int ldc, int nbound)
{
  __shared__ u16 As[128*64];
  __shared__ u16 Bs[128*64];
  const int tid  = threadIdx.x;
  const int lane = tid & 63;
  const int wid  = tid >> 6;

  const int nbx = gridDim.x;
  const int nwg = nbx * gridDim.y;
  const int bid = blockIdx.y * nbx + blockIdx.x;
  const int cpx = nwg >> 3;
  const int swzb = (bid & 7) * cpx + (bid >> 3);
  const int bx = swzb % nbx, by = swzb / nbx;

  const int m0 = by * 128;
  const int n0 = bx * 128;
  const int wr = wid >> 1, wc = wid & 1;
  f32x4 acc[4][4] = {};

  const int srow = lane >> 3;
  const int skel = (lane & 7) * 8;

  for (int kt = 0; kt < K; kt += 64) {
    #pragma unroll
    for (int i=0;i<4;++i){
      int seg  = wid*4 + i;
      int arow = seg*8 + srow;
      gload16(A  + (size_t)(m0 + arow)*K + kt + skel, As + seg*512);
      gload16(BT + (size_t)(n0 + arow)*K + kt + skel, Bs + seg*512);
    }
    __syncthreads();
    #pragma unroll
    for (int ks=0; ks<2; ++ks){
      bf16x8 a[4], b[4];
      #pragma unroll
      for (int m=0;m<4;++m){
        int off = (wr*64 + m*16 + (lane&15))*64 + ks*32 + (lane>>4)*8;
        a[m] = __builtin_bit_cast(bf16x8, *(const s16x8*)(As + off));
      }
      #pragma unroll
      for (int n=0;n<4;++n){
        int off = (wc*64 + n*16 + (lane&15))*64 + ks*32 + (lane>>4)*8;
        b[n] = __builtin_bit_cast(bf16x8, *(const s16x8*)(Bs + off));
      }
      #pragma unroll
      for (int m=0;m<4;++m)
        #pragma unroll
        for (int n=0;n<4;++n)
          acc[m][n] = __builtin_amdgcn_mfma_f32_16x16x32_bf16(a[m], b[n], acc[m][n], 0,0,0);
    }
    __syncthreads();
  }

  #pragma unroll
  for (int m=0;m<4;++m){
    #pragma unroll
    for (int n=0;n<4;++n){
      int col = n0 + wc*64 + n*16 + (lane & 15);
      #pragma unroll
      for (int i=0;i<4;++i){
        int row = m0 + wr*64 + m*16 + ((lane>>4)<<2) + i;
        float v = acc[m][n][i];
        if (OUT_F32) {
          if (col < nbound){
            float bv = HAS_BIAS ? bias[col] : 0.f;
            ((float*)Cv)[(size_t)row*ldc + col] = v + bv;
          }
        } else {
          ((u16*)Cv)[(size_t)row*ldc + col] = f2b(v);
        }
      }
    }
  }
}

// ---------------- SRU scan v3 (R12, best): 8 steps/iter, one vmcnt + one lgkm --
template<int KG>
__global__ __launch_bounds__(64) void k_scan(
    const u16* __restrict__ U, const u16* __restrict__ hwsrc,
    const float* __restrict__ v, const float* __restrict__ bb,
    u16* __restrict__ hout, float* __restrict__ states)
{
  constexpr int NS = 4;            // ring slots (4KB each)
  constexpr int D  = 3;            // prefetch distance in iters (24 steps)
  constexpr int NI = T_LEN/8;      // 64 iterations, 8 steps each
  __shared__ u16 ring[NS*2048];    // 16 KB

  const int lane = threadIdx.x;
  const int bid  = blockIdx.x;
  const int hblk = bid & 7;
  const int b    = (bid >> 3) & 31;
  const int d    = bid >> 8;
  const int h    = hblk*64 + lane;
  const int RS   = 2*KG*HDIM;

  const int s2 = lane >> 5, p = (lane>>3)&3, c7 = lane&7;

  auto issue = [&](int k, int slot){
    #pragma unroll
    for (int half=0; half<4; ++half){
      int s = 8*k + 2*half + s2;
      int t = d ? (T_LEN-1-s) : s;
      int row = t*BATCH + b;
      const u16* g;
      if (KG == 4 || p < 3)
        g = U + (size_t)row*RS + (size_t)(d*KG + p)*HDIM + hblk*64 + c7*8;
      else
        g = hwsrc + (size_t)row*HDIM + hblk*64 + c7*8;
      gload16(g, &ring[slot*2048 + half*512]);
    }
  };
  auto ldslot = [&](int k, float (&xq)[8], float (&fq)[8], float (&rq)[8], float (&wq)[8]){
    const u16* base = ring + (k & (NS-1))*2048;
    #pragma unroll
    for (int j=0;j<8;++j){
      xq[j] = b2f(base[j*256 + 0*64 + lane]);
      fq[j] = b2f(base[j*256 + 1*64 + lane]);
      rq[j] = b2f(base[j*256 + 2*64 + lane]);
      wq[j] = b2f(base[j*256 + 3*64 + lane]);
    }
  };

  for (int k=0;k<D;++k) issue(k, k);
  asm volatile("s_waitcnt vmcnt(0)" ::: "memory");
  __builtin_amdgcn_sched_barrier(0);

  const float vf  = v[(d*2+0)*HDIM + h];
  const float vr  = v[(d*2+1)*HDIM + h];
  const float bf_ = bb[(d*2+0)*HDIM + h];
  const float br_ = bb[(d*2+1)*HDIM + h];

  float xA[8], fA[8], rA[8], wA[8];
  float xB[8], fB[8], rB[8], wB[8];
  ldslot(0, xA, fA, rA, wA);
  asm volatile("s_waitcnt lgkmcnt(0)" ::: "memory");
  __builtin_amdgcn_sched_barrier(0);

  float cst = 0.f;
  auto compute8 = [&](int k, float (&xq)[8], float (&fq)[8], float (&rq)[8], float (&wq)[8]){
    #pragma unroll
    for (int j=0;j<8;++j){
      int s = 8*k + j;
      int t = d ? (T_LEN-1-s) : s;
      float f = sigmoidf_(fq[j] + vf*cst + bf_);
      float r = sigmoidf_(rq[j] + vr*cst + br_);
      cst = xq[j] + f*(cst - xq[j]);
      float hv = wq[j] + r*(tanhf_(cst) - wq[j]);
      hout[(size_t)(t*BATCH + b)*(2*HDIM) + d*HDIM + h] = f2b(hv);
    }
  };

  for (int k=0; k<NI; k+=2){
    {
      int kk = (k+D < NI) ? (k+D) : (NI-1);
      issue(kk, (k+D) & (NS-1));
      asm volatile("s_waitcnt vmcnt(24)" ::: "memory");
      __builtin_amdgcn_sched_barrier(0);
      ldslot(k+1, xB, fB, rB, wB);
      __builtin_amdgcn_sched_barrier(0);
      compute8(k, xA, fA, rA, wA);
      asm volatile("s_waitcnt lgkmcnt(0)" ::: "memory");
      __builtin_amdgcn_sched_barrier(0);
    }
    {
      int kk = (k+1+D < NI) ? (k+1+D) : (NI-1);
      issue(kk, (k+1+D) & (NS-1));
      asm volatile("s_waitcnt vmcnt(24)" ::: "memory");
      __builtin_amdgcn_sched_barrier(0);
      if (k+2 < NI) ldslot(k+2, xA, fA, rA, wA);
      __builtin_amdgcn_sched_barrier(0);
      compute8(k+1, xB, fB, rB, wB);
      asm volatile("s_waitcnt lgkmcnt(0)" ::: "memory");
      __builtin_amdgcn_sched_barrier(0);
    }
  }
  states[(size_t)b*(2*HDIM) + d*HDIM + h] = cst;
}

// ---------------- launch ----------------
extern "C" void kernel_launch(void* const* d_in, const int* in_sizes, int n_in,
                              void* d_out, int out_size, void* d_ws, size_t ws_size,
                              hipStream_t stream)
{
  const float* x   = (const float*)d_in[0];
  const float* W1  = (const float*)d_in[1];
  const float* b1  = (const float*)d_in[2];
  const float* W2  = (const float*)d_in[3];
  const float* b2  = (const float*)d_in[4];
  const float* W0  = (const float*)d_in[5];
  const float* v0  = (const float*)d_in[6];
  const float* bb0 = (const float*)d_in[7];
  const float* g0  = (const float*)d_in[8];
  const float* be0 = (const float*)d_in[9];
  const float* Ws  = (const float*)d_in[10];
  const float* vs  = (const float*)d_in[11];
  const float* bbs = (const float*)d_in[12];
  const float* gs  = (const float*)d_in[13];
  const float* bes = (const float*)d_in[14];
  (void)in_sizes; (void)n_in; (void)out_size; (void)ws_size;

  char* ws = (char*)d_ws;
  size_t off = 0;
  auto alloc = [&](size_t bytes)->void*{
    void* p = ws + off; off += (bytes + 255) & ~(size_t)255; return p;
  };
  u16* W0T  = (u16*)alloc((size_t)3072*512*2);
  u16* WsT  = (u16*)alloc((size_t)4*4096*1024*2);
  u16* W2T  = (u16*)alloc((size_t)128*1024*2);
  u16* h0   = (u16*)alloc((size_t)MROWS*512*2);
  u16* xn   = (u16*)alloc((size_t)MROWS*1024*2);
  u16* Ubuf = (u16*)alloc((size_t)MROWS*4096*2);
  u16* hbuf = (u16*)alloc((size_t)MROWS*1024*2);

  float* outp   = (float*)d_out;
  float* states = outp + (size_t)MROWS*NOUT;

  // --- weight prep (every call; deterministic) ---
  hipMemsetAsync(W2T, 0, (size_t)128*1024*2, stream);
  k_transpose_cast<<<dim3(3072/32, 512/32), dim3(32,8), 0, stream>>>(W0, W0T, 512, 3072, 512);
  for (int i=0;i<4;++i)
    k_transpose_cast<<<dim3(4096/32, 1024/32), dim3(32,8), 0, stream>>>(
        Ws + (size_t)i*1024*4096, WsT + (size_t)i*4096*1024, 1024, 4096, 1024);
  k_transpose_cast<<<dim3(3, 1024/32), dim3(32,8), 0, stream>>>(W2, W2T, 1024, NOUT, 1024);

  // --- input projection ---
  k_gemm1_relu<<<dim3(HDIM/64, MROWS/64), 256, 0, stream>>>(x, W1, b1, h0);

  // --- layer 0 (k=3, highway = layer input h0) ---
  k_ln<512><<<MROWS/4, 256, 0, stream>>>(h0, g0, be0, xn);
  k_gemm256<<<dim3(3072/256, MROWS/256), 1024, 0, stream>>>(xn, W0T, Ubuf, 512, 3072);
  k_scan<3><<<512, 64, 0, stream>>>(Ubuf, h0, v0, bb0, hbuf, states);

  // --- layers 1..4 (k=4, highway = U[...,3]) ---
  for (int i=0;i<4;++i){
    k_ln<1024><<<MROWS/4, 256, 0, stream>>>(hbuf, gs + (size_t)i*1024, bes + (size_t)i*1024, xn);
    k_gemm256<<<dim3(4096/256, MROWS/256), 1024, 0, stream>>>(
        xn, WsT + (size_t)i*4096*1024, Ubuf, 1024, 4096);
    k_scan<4><<<512, 64, 0, stream>>>(Ubuf, nullptr, vs + (size_t)i*2048, bbs + (size_t)i*2048,
                                      hbuf, states + (size_t)(i+1)*BATCH*1024);
  }

  // --- output projection (N padded to 128, bound 90, f32 out + bias) ---
  k_gemm<true,true><<<dim3(1, MROWS/128), 256, 0, stream>>>(
      hbuf, W2T, d_out, b2, 1024, 128, NOUT, NOUT);
}

// Round 14
// 1060.617 us; speedup vs baseline: 1.1669x; 1.1669x over previous
//
#include <hip/hip_runtime.h>
#include <stdint.h>

#define T_LEN 512
#define BATCH 32
#define NIN   72
#define NOUT  90
#define HDIM  512
#define MROWS (T_LEN*BATCH)   // 16384

typedef unsigned short u16;
typedef unsigned int   u32;

typedef __bf16 bf16x8 __attribute__((ext_vector_type(8)));
typedef short  s16x8  __attribute__((ext_vector_type(8)));
typedef float  f32x4  __attribute__((ext_vector_type(4)));

__device__ __forceinline__ float b2f(u16 u){ return __uint_as_float(((u32)u)<<16); }
__device__ __forceinline__ u16 f2b(float x){
  u32 u = __float_as_uint(x);
  u += 0x7FFFu + ((u>>16)&1u);          // RNE
  return (u16)(u>>16);
}

__device__ __forceinline__ void gload16(const void* g, void* l){
  __builtin_amdgcn_global_load_lds(
      (const __attribute__((address_space(1))) void*)g,
      (__attribute__((address_space(3))) void*)l, 16, 0, 0);
}

// ---------------- transpose + cast: (K,N) f32 -> (N,K) bf16 ----------------
__global__ __launch_bounds__(256) void k_transpose_cast(
    const float* __restrict__ S, u16* __restrict__ D, int K, int N, int ldd)
{
  __shared__ float t[32][33];
  int k0 = blockIdx.y*32, n0 = blockIdx.x*32;
  int tx = threadIdx.x, ty = threadIdx.y;   // 32 x 8
  #pragma unroll
  for (int i=0;i<4;++i){
    int k = k0 + ty + i*8, n = n0 + tx;
    if (k < K && n < N) t[ty+i*8][tx] = S[(size_t)k*N + n];
  }
  __syncthreads();
  #pragma unroll
  for (int i=0;i<4;++i){
    int n = n0 + ty + i*8, k = k0 + tx;
    if (n < N && k < K) D[(size_t)n*ldd + k] = f2b(t[tx][ty+i*8]);
  }
}

// ---------------- input projection: relu(x@W1+b1) -> bf16 ----------------
__global__ __launch_bounds__(256) void k_gemm1_relu(
    const float* __restrict__ X, const float* __restrict__ W1,
    const float* __restrict__ b1, u16* __restrict__ H0)
{
  __shared__ float As[64][73];
  __shared__ float Bs[72][64];
  int m0 = blockIdx.y*64, n0 = blockIdx.x*64;
  int tid = threadIdx.x;
  for (int idx=tid; idx<64*NIN; idx+=256){ int r=idx/NIN, k=idx-r*NIN; As[r][k] = X[(size_t)(m0+r)*NIN + k]; }
  for (int idx=tid; idx<NIN*64; idx+=256){ int k=idx>>6, n=idx&63; Bs[k][n] = W1[(size_t)k*HDIM + n0+n]; }
  __syncthreads();
  int tx = tid & 15, ty = tid >> 4;
  float acc[4][4] = {};
  for (int k=0;k<NIN;++k){
    float a[4], bv[4];
    #pragma unroll
    for (int i=0;i<4;++i) a[i]=As[ty*4+i][k];
    #pragma unroll
    for (int j=0;j<4;++j) bv[j]=Bs[k][tx*4+j];
    #pragma unroll
    for (int i=0;i<4;++i)
      #pragma unroll
      for (int j=0;j<4;++j) acc[i][j] += a[i]*bv[j];
  }
  #pragma unroll
  for (int i=0;i<4;++i){
    int row = m0 + ty*4 + i;
    #pragma unroll
    for (int j=0;j<4;++j){
      int col = n0 + tx*4 + j;
      float v = acc[i][j] + b1[col];
      H0[(size_t)row*HDIM + col] = f2b(v > 0.f ? v : 0.f);
    }
  }
}

// ---------------- LayerNorm (bf16 in -> bf16 out), one wave per row ----------------
template<int D>
__global__ __launch_bounds__(256) void k_ln(
    const u16* __restrict__ X, const float* __restrict__ g,
    const float* __restrict__ be, u16* __restrict__ Y)
{
  int wrow = (blockIdx.x*256 + threadIdx.x) >> 6;
  int lane = threadIdx.x & 63;
  constexpr int E = D/64;
  const u16* row = X + (size_t)wrow*D;
  float vals[E];
  float s=0.f, s2=0.f;
  #pragma unroll
  for (int i=0;i<E/4;++i){
    ushort4 u = *(const ushort4*)(row + i*256 + lane*4);
    float v0=b2f(u.x), v1=b2f(u.y), v2=b2f(u.z), v3=b2f(u.w);
    vals[i*4+0]=v0; vals[i*4+1]=v1; vals[i*4+2]=v2; vals[i*4+3]=v3;
    s  += v0+v1+v2+v3;
    s2 += v0*v0+v1*v1+v2*v2+v3*v3;
  }
  #pragma unroll
  for (int off=32; off; off>>=1){ s += __shfl_xor(s,off); s2 += __shfl_xor(s2,off); }
  float mean = s * (1.f/D);
  float var  = s2 * (1.f/D) - mean*mean;
  float rstd = rsqrtf(var + 1e-5f);
  u16* yr = Y + (size_t)wrow*D;
  #pragma unroll
  for (int i=0;i<E/4;++i){
    int col = i*256 + lane*4;
    float4 gg = *(const float4*)(g+col);
    float4 bb = *(const float4*)(be+col);
    ushort4 o;
    o.x = f2b((vals[i*4+0]-mean)*rstd*gg.x + bb.x);
    o.y = f2b((vals[i*4+1]-mean)*rstd*gg.y + bb.y);
    o.z = f2b((vals[i*4+2]-mean)*rstd*gg.z + bb.z);
    o.w = f2b((vals[i*4+3]-mean)*rstd*gg.w + bb.w);
    *(ushort4*)(yr + col) = o;
  }
}

// ======== 256x256 bf16 MFMA GEMM (R7/R9/R12 proven 134us): single barrier/tile,
// ds_read issues hoisted ahead of MFMA clusters, B frags double-buffered. =======
__global__ __launch_bounds__(512, 2) void k_gemm256(
    const u16* __restrict__ A, const u16* __restrict__ BT,
    u16* __restrict__ C, int K, int N)
{
  __shared__ u16 lds[65536];   // 128 KiB
  const int tid  = threadIdx.x;
  const int lane = tid & 63;
  const int wid  = tid >> 6;        // 0..7
  const int wm   = wid >> 2;        // 0..1
  const int wn   = wid & 3;         // 0..3

  // XCD-aware bijective swizzle (nwg % 8 == 0 for all launches)
  const int nbx = gridDim.x;
  const int nwg = nbx * gridDim.y;
  const int bid = blockIdx.y * nbx + blockIdx.x;
  const int cpx = nwg >> 3;
  const int swz = (bid & 7) * cpx + (bid >> 3);
  const int m0 = (swz / nbx) * 256;
  const int n0 = (swz % nbx) * 256;

  const int l3 = lane >> 3, l7 = lane & 7;
  const int kswz = (l7 ^ l3) * 8;   // pre-swizzled k-element offset for staging

  auto stageA = [&](int ts, int h, int db){
    const u16* base = A + (size_t)(m0 + h*128 + wid*8 + l3)*K + ts*64 + kswz;
    u16* dst = lds + db*32768 + h*8192 + wid*512;
    gload16(base,               dst);
    gload16(base + (size_t)64*K, dst + 4096);
  };
  auto stageB = [&](int ts, int db){
    const u16* base = BT + (size_t)(n0 + wid*8 + l3)*K + ts*64 + kswz;
    u16* dst = lds + db*32768 + 16384 + wid*512;
    gload16(base,                dst);
    gload16(base + (size_t) 64*K, dst + 4096);
    gload16(base + (size_t)128*K, dst + 8192);
    gload16(base + (size_t)192*K, dst + 12288);
  };
  auto rdfrag = [&](const u16* buf, int row, int ks)->bf16x8 {
    int byte = (row*128 + (ks*32 + ((lane>>4)*8))*2) ^ ((row&7)<<4);
    return __builtin_bit_cast(bf16x8, *(const s16x8*)((const char*)buf + byte));
  };

  f32x4 acc[8][4] = {};
  bf16x8 afr[2][2][2];    // [parity][mm][ks], static indexing
  bf16x8 bfr0[4][2], bfr1[4][2];
  const int nt = K >> 6;  // 8 or 16 (always even)

  // prologue: stage tile 0, drain, read B(0)->bfr0 and A0(0)->afr[0]
  stageA(0, 0, 0);
  stageA(0, 1, 0);
  stageB(0, 0);
  asm volatile("s_waitcnt vmcnt(0)" ::: "memory");
  __builtin_amdgcn_sched_barrier(0);
  __builtin_amdgcn_s_barrier();
  __builtin_amdgcn_sched_barrier(0);
  #pragma unroll
  for (int n=0;n<4;++n)
    #pragma unroll
    for (int ks=0;ks<2;++ks)
      bfr0[n][ks] = rdfrag(lds + 16384, wn*64 + n*16 + (lane&15), ks);
  #pragma unroll
  for (int mm=0;mm<2;++mm)
    #pragma unroll
    for (int ks=0;ks<2;++ks)
      afr[0][mm][ks] = rdfrag(lds, wm*128 + mm*16 + (lane&15), ks);

  auto tile = [&](int t, bf16x8 (&bcur)[4][2], bf16x8 (&bnxt)[4][2]){
    const u16* bufA  = lds + (t & 1)*32768;
    const int  tn    = (t+1 < nt) ? t+1 : t;   // tail: dummy re-stage keeps counts uniform
    const int  db    = (t+1) & 1;
    const u16* bufAn = lds + db*32768;
    const u16* bufBn = bufAn + 16384;

    // TOP: stage tile t+1 (8 loads)
    stageA(tn, 0, db);
    stageA(tn, 1, db);
    stageB(tn, db);

    // q0..q2: wait own frags (issued >=1 cluster ago) -> issue A(q+1) -> MFMA q
    #pragma unroll
    for (int q=0;q<3;++q){
      asm volatile("s_waitcnt lgkmcnt(0)" ::: "memory");
      __builtin_amdgcn_sched_barrier(0);
      #pragma unroll
      for (int mm=0;mm<2;++mm)
        #pragma unroll
        for (int ks=0;ks<2;++ks)
          afr[(q+1)&1][mm][ks] = rdfrag(bufA, wm*128 + ((q+1)*2+mm)*16 + (lane&15), ks);
      __builtin_amdgcn_sched_barrier(0);   // pin read-issue BEFORE the MFMA cluster
      __builtin_amdgcn_s_setprio(1);
      #pragma unroll
      for (int mm=0;mm<2;++mm)
        #pragma unroll
        for (int n=0;n<4;++n)
          #pragma unroll
          for (int ks=0;ks<2;++ks)
            acc[q*2+mm][n] = __builtin_amdgcn_mfma_f32_16x16x32_bf16(
                afr[q&1][mm][ks], bcur[n][ks], acc[q*2+mm][n], 0,0,0);
      __builtin_amdgcn_s_setprio(0);
    }

    // q3: drain loads (t+1 landed) + own A3 reads, ONE barrier, then issue
    // A0(t+1)+B(t+1) reads BEFORE the q3 MFMA cluster.
    asm volatile("s_waitcnt vmcnt(0) lgkmcnt(0)" ::: "memory");
    __builtin_amdgcn_sched_barrier(0);
    __builtin_amdgcn_s_barrier();
    __builtin_amdgcn_sched_barrier(0);
    #pragma unroll
    for (int mm=0;mm<2;++mm)
      #pragma unroll
      for (int ks=0;ks<2;++ks)
        afr[0][mm][ks] = rdfrag(bufAn, wm*128 + mm*16 + (lane&15), ks);
    #pragma unroll
    for (int n=0;n<4;++n)
      #pragma unroll
      for (int ks=0;ks<2;++ks)
        bnxt[n][ks] = rdfrag(bufBn, wn*64 + n*16 + (lane&15), ks);
    __builtin_amdgcn_sched_barrier(0);   // pin read-issue BEFORE the MFMA cluster
    __builtin_amdgcn_s_setprio(1);
    #pragma unroll
    for (int mm=0;mm<2;++mm)
      #pragma unroll
      for (int n=0;n<4;++n)
        #pragma unroll
        for (int ks=0;ks<2;++ks)
          acc[6+mm][n] = __builtin_amdgcn_mfma_f32_16x16x32_bf16(
              afr[1][mm][ks], bcur[n][ks], acc[6+mm][n], 0,0,0);
    __builtin_amdgcn_s_setprio(0);
  };

  for (int t = 0; t < nt; t += 2){
    tile(t,   bfr0, bfr1);
    tile(t+1, bfr1, bfr0);
  }

  // epilogue: C write (bf16)
  #pragma unroll
  for (int m=0;m<8;++m){
    int row = m0 + wm*128 + m*16 + ((lane>>4)<<2);
    #pragma unroll
    for (int n=0;n<4;++n){
      int col = n0 + wn*64 + n*16 + (lane&15);
      #pragma unroll
      for (int i=0;i<4;++i)
        C[(size_t)(row+i)*N + col] = f2b(acc[m][n][i]);
    }
  }
}

// ---------------- old 128x128 GEMM (kept for the small out-projection) ----------------
template<bool OUT_F32, bool HAS_BIAS>
__global__ __launch_bounds__(256) void k_gemm(
    const u16* __restrict__ A, const u16* __restrict__ BT,
    void* __restrict__ Cv, const float* __restrict__ bias,
    int K, int N, int ldc, int nbound)
{
  __shared__ u16 As[128*64];
  __shared__ u16 Bs[128*64];
  const int tid  = threadIdx.x;
  const int lane = tid & 63;
  const int wid  = tid >> 6;

  const int nbx = gridDim.x;
  const int nwg = nbx * gridDim.y;
  const int bid = blockIdx.y * nbx + blockIdx.x;
  const int cpx = nwg >> 3;
  const int swzb = (bid & 7) * cpx + (bid >> 3);
  const int bx = swzb % nbx, by = swzb / nbx;

  const int m0 = by * 128;
  const int n0 = bx * 128;
  const int wr = wid >> 1, wc = wid & 1;
  f32x4 acc[4][4] = {};

  const int srow = lane >> 3;
  const int skel = (lane & 7) * 8;

  for (int kt = 0; kt < K; kt += 64) {
    #pragma unroll
    for (int i=0;i<4;++i){
      int seg  = wid*4 + i;
      int arow = seg*8 + srow;
      gload16(A  + (size_t)(m0 + arow)*K + kt + skel, As + seg*512);
      gload16(BT + (size_t)(n0 + arow)*K + kt + skel, Bs + seg*512);
    }
    __syncthreads();
    #pragma unroll
    for (int ks=0; ks<2; ++ks){
      bf16x8 a[4], b[4];
      #pragma unroll
      for (int m=0;m<4;++m){
        int off = (wr*64 + m*16 + (lane&15))*64 + ks*32 + (lane>>4)*8;
        a[m] = __builtin_bit_cast(bf16x8, *(const s16x8*)(As + off));
      }
      #pragma unroll
      for (int n=0;n<4;++n){
        int off = (wc*64 + n*16 + (lane&15))*64 + ks*32 + (lane>>4)*8;
        b[n] = __builtin_bit_cast(bf16x8, *(const s16x8*)(Bs + off));
      }
      #pragma unroll
      for (int m=0;m<4;++m)
        #pragma unroll
        for (int n=0;n<4;++n)
          acc[m][n] = __builtin_amdgcn_mfma_f32_16x16x32_bf16(a[m], b[n], acc[m][n], 0,0,0);
    }
    __syncthreads();
  }

  #pragma unroll
  for (int m=0;m<4;++m){
    #pragma unroll
    for (int n=0;n<4;++n){
      int col = n0 + wc*64 + n*16 + (lane & 15);
      #pragma unroll
      for (int i=0;i<4;++i){
        int row = m0 + wr*64 + m*16 + ((lane>>4)<<2) + i;
        float v = acc[m][n][i];
        if (OUT_F32) {
          if (col < nbound){
            float bv = HAS_BIAS ? bias[col] : 0.f;
            ((float*)Cv)[(size_t)row*ldc + col] = v + bv;
          }
        } else {
          ((u16*)Cv)[(size_t)row*ldc + col] = f2b(v);
        }
      }
    }
  }
}

// ---------------- SRU scan v4: v3 ring/pipeline + slim arithmetic ----------
// The scan is ISSUE-bound (2 waves/CU structural): without fast-math each
// sigmoid/tanh division compiled to the ~8-instr v_div sequence (3 per step)
// and the manual RNE pack is 5 instr.  v4: v_rcp_f32 via builtin (1 ulp, safe:
// outputs are bf16 and the recurrence is contracting), bias-sums precomputed
// in ldslot (off the serial chain), tanh = 1 - 2*rcp(1+e^{2c}) (inf-safe),
// native __bf16 cast (v_cvt, RNE).  ~35 -> ~20 instr/step.
template<int KG>
__global__ __launch_bounds__(64) void k_scan(
    const u16* __restrict__ U, const u16* __restrict__ hwsrc,
    const float* __restrict__ v, const float* __restrict__ bb,
    u16* __restrict__ hout, float* __restrict__ states)
{
  constexpr int NS = 4;            // ring slots (4KB each)
  constexpr int D  = 3;            // prefetch distance in iters (24 steps)
  constexpr int NI = T_LEN/8;      // 64 iterations, 8 steps each
  __shared__ u16 ring[NS*2048];    // 16 KB

  const int lane = threadIdx.x;
  const int bid  = blockIdx.x;
  const int hblk = bid & 7;
  const int b    = (bid >> 3) & 31;
  const int d    = bid >> 8;
  const int h    = hblk*64 + lane;
  const int RS   = 2*KG*HDIM;

  const int s2 = lane >> 5, p = (lane>>3)&3, c7 = lane&7;

  auto issue = [&](int k, int slot){
    #pragma unroll
    for (int half=0; half<4; ++half){
      int s = 8*k + 2*half + s2;
      int t = d ? (T_LEN-1-s) : s;
      int row = t*BATCH + b;
      const u16* g;
      if (KG == 4 || p < 3)
        g = U + (size_t)row*RS + (size_t)(d*KG + p)*HDIM + hblk*64 + c7*8;
      else
        g = hwsrc + (size_t)row*HDIM + hblk*64 + c7*8;
      gload16(g, &ring[slot*2048 + half*512]);
    }
  };

  const float vf  = v[(d*2+0)*HDIM + h];
  const float vr  = v[(d*2+1)*HDIM + h];
  const float bf_ = bb[(d*2+0)*HDIM + h];
  const float br_ = bb[(d*2+1)*HDIM + h];
  const float vfn = -vf, vrn = -vr;

  // per-slot register banks: x, af=-(f+bf), ar=-(r+br), w, w1=1-w
  auto ldslot = [&](int k, float (&xq)[8], float (&af)[8], float (&ar)[8],
                    float (&wq)[8], float (&w1)[8]){
    const u16* base = ring + (k & (NS-1))*2048;
    #pragma unroll
    for (int j=0;j<8;++j){
      xq[j] = b2f(base[j*256 + 0*64 + lane]);
      af[j] = -(b2f(base[j*256 + 1*64 + lane]) + bf_);
      ar[j] = -(b2f(base[j*256 + 2*64 + lane]) + br_);
      float w = b2f(base[j*256 + 3*64 + lane]);
      wq[j] = w; w1[j] = 1.f - w;
    }
  };

  for (int k=0;k<D;++k) issue(k, k);
  asm volatile("s_waitcnt vmcnt(0)" ::: "memory");
  __builtin_amdgcn_sched_barrier(0);

  float xA[8], fA[8], rA[8], wA[8], w1A[8];
  float xB[8], fB[8], rB[8], wB[8], w1B[8];
  ldslot(0, xA, fA, rA, wA, w1A);
  asm volatile("s_waitcnt lgkmcnt(0)" ::: "memory");
  __builtin_amdgcn_sched_barrier(0);

  float cst = 0.f;
  auto compute8 = [&](int k, float (&xq)[8], float (&af)[8], float (&ar)[8],
                      float (&wq)[8], float (&w1)[8]){
    #pragma unroll
    for (int j=0;j<8;++j){
      int s = 8*k + j;
      int t = d ? (T_LEN-1-s) : s;
      // f = sigmoid(fq + vf*c + bf) = rcp(1 + exp(-(fq+bf) - vf*c))
      float f = __builtin_amdgcn_rcpf(1.f + __expf(fmaf(vfn, cst, af[j])));
      float r = __builtin_amdgcn_rcpf(1.f + __expf(fmaf(vrn, cst, ar[j])));
      cst = fmaf(f, cst - xq[j], xq[j]);                 // f*c + (1-f)*x
      // tanh(c2) = 1 - 2*rcp(1+e^{2c2});  h = w + r*(tanh - w) = w + r*(w1 - 2p)
      float pE = __builtin_amdgcn_rcpf(1.f + __expf(cst * 2.f));
      float hv = fmaf(r, fmaf(-2.f, pE, w1[j]), wq[j]);
      hout[(size_t)(t*BATCH + b)*(2*HDIM) + d*HDIM + h] =
          __builtin_bit_cast(u16, (__bf16)hv);           // native RNE cvt
    }
  };

  for (int k=0; k<NI; k+=2){
    {
      int kk = (k+D < NI) ? (k+D) : (NI-1);
      issue(kk, (k+D) & (NS-1));
      asm volatile("s_waitcnt vmcnt(24)" ::: "memory");   // slot k+1 loads retired
      __builtin_amdgcn_sched_barrier(0);
      ldslot(k+1, xB, fB, rB, wB, w1B);                   // ds_reads issue EARLY
      __builtin_amdgcn_sched_barrier(0);
      compute8(k, xA, fA, rA, wA, w1A);                   // hides ds_read latency
      asm volatile("s_waitcnt lgkmcnt(0)" ::: "memory");  // bank B ready
      __builtin_amdgcn_sched_barrier(0);
    }
    {
      int kk = (k+1+D < NI) ? (k+1+D) : (NI-1);
      issue(kk, (k+1+D) & (NS-1));
      asm volatile("s_waitcnt vmcnt(24)" ::: "memory");
      __builtin_amdgcn_sched_barrier(0);
      if (k+2 < NI) ldslot(k+2, xA, fA, rA, wA, w1A);
      __builtin_amdgcn_sched_barrier(0);
      compute8(k+1, xB, fB, rB, wB, w1B);
      asm volatile("s_waitcnt lgkmcnt(0)" ::: "memory");
      __builtin_amdgcn_sched_barrier(0);
    }
  }
  states[(size_t)b*(2*HDIM) + d*HDIM + h] = cst;
}

// ---------------- launch ----------------
extern "C" void kernel_launch(void* const* d_in, const int* in_sizes, int n_in,
                              void* d_out, int out_size, void* d_ws, size_t ws_size,
                              hipStream_t stream)
{
  const float* x   = (const float*)d_in[0];
  const float* W1  = (const float*)d_in[1];
  const float* b1  = (const float*)d_in[2];
  const float* W2  = (const float*)d_in[3];
  const float* b2  = (const float*)d_in[4];
  const float* W0  = (const float*)d_in[5];
  const float* v0  = (const float*)d_in[6];
  const float* bb0 = (const float*)d_in[7];
  const float* g0  = (const float*)d_in[8];
  const float* be0 = (const float*)d_in[9];
  const float* Ws  = (const float*)d_in[10];
  const float* vs  = (const float*)d_in[11];
  const float* bbs = (const float*)d_in[12];
  const float* gs  = (const float*)d_in[13];
  const float* bes = (const float*)d_in[14];
  (void)in_sizes; (void)n_in; (void)out_size; (void)ws_size;

  char* ws = (char*)d_ws;
  size_t off = 0;
  auto alloc = [&](size_t bytes)->void*{
    void* p = ws + off; off += (bytes + 255) & ~(size_t)255; return p;
  };
  u16* W0T  = (u16*)alloc((size_t)3072*512*2);
  u16* WsT  = (u16*)alloc((size_t)4*4096*1024*2);
  u16* W2T  = (u16*)alloc((size_t)128*1024*2);
  u16* h0   = (u16*)alloc((size_t)MROWS*512*2);
  u16* xn   = (u16*)alloc((size_t)MROWS*1024*2);
  u16* Ubuf = (u16*)alloc((size_t)MROWS*4096*2);
  u16* hbuf = (u16*)alloc((size_t)MROWS*1024*2);

  float* outp   = (float*)d_out;
  float* states = outp + (size_t)MROWS*NOUT;

  // --- weight prep (every call; deterministic) ---
  hipMemsetAsync(W2T, 0, (size_t)128*1024*2, stream);
  k_transpose_cast<<<dim3(3072/32, 512/32), dim3(32,8), 0, stream>>>(W0, W0T, 512, 3072, 512);
  for (int i=0;i<4;++i)
    k_transpose_cast<<<dim3(4096/32, 1024/32), dim3(32,8), 0, stream>>>(
        Ws + (size_t)i*1024*4096, WsT + (size_t)i*4096*1024, 1024, 4096, 1024);
  k_transpose_cast<<<dim3(3, 1024/32), dim3(32,8), 0, stream>>>(W2, W2T, 1024, NOUT, 1024);

  // --- input projection ---
  k_gemm1_relu<<<dim3(HDIM/64, MROWS/64), 256, 0, stream>>>(x, W1, b1, h0);

  // --- layer 0 (k=3, highway = layer input h0) ---
  k_ln<512><<<MROWS/4, 256, 0, stream>>>(h0, g0, be0, xn);
  k_gemm256<<<dim3(3072/256, MROWS/256), 512, 0, stream>>>(xn, W0T, Ubuf, 512, 3072);
  k_scan<3><<<512, 64, 0, stream>>>(Ubuf, h0, v0, bb0, hbuf, states);

  // --- layers 1..4 (k=4, highway = U[...,3]) ---
  for (int i=0;i<4;++i){
    k_ln<1024><<<MROWS/4, 256, 0, stream>>>(hbuf, gs + (size_t)i*1024, bes + (size_t)i*1024, xn);
    k_gemm256<<<dim3(4096/256, MROWS/256), 512, 0, stream>>>(
        xn, WsT + (size_t)i*4096*1024, Ubuf, 1024, 4096);
    k_scan<4><<<512, 64, 0, stream>>>(Ubuf, nullptr, vs + (size_t)i*2048, bbs + (size_t)i*2048,
                                      hbuf, states + (size_t)(i+1)*BATCH*1024);
  }

  // --- output projection (N padded to 128, bound 90, f32 out + bias) ---
  k_gemm<true,true><<<dim3(1, MROWS/128), 256, 0, stream>>>(
      hbuf, W2T, d_out, b2, 1024, 128, NOUT, NOUT);
}

// Round 15
// 1060.007 us; speedup vs baseline: 1.1676x; 1.0006x over previous
//
#include <hip/hip_runtime.h>
#include <stdint.h>

#define T_LEN 512
#define BATCH 32
#define NIN   72
#define NOUT  90
#define HDIM  512
#define MROWS (T_LEN*BATCH)   // 16384

typedef unsigned short u16;
typedef unsigned int   u32;

typedef __bf16 bf16x8 __attribute__((ext_vector_type(8)));
typedef short  s16x8  __attribute__((ext_vector_type(8)));
typedef float  f32x4  __attribute__((ext_vector_type(4)));

__device__ __forceinline__ float b2f(u16 u){ return __uint_as_float(((u32)u)<<16); }
__device__ __forceinline__ u16 f2b(float x){
  u32 u = __float_as_uint(x);
  u += 0x7FFFu + ((u>>16)&1u);          // RNE
  return (u16)(u>>16);
}

__device__ __forceinline__ void gload16(const void* g, void* l){
  __builtin_amdgcn_global_load_lds(
      (const __attribute__((address_space(1))) void*)g,
      (__attribute__((address_space(3))) void*)l, 16, 0, 0);
}

// ---------------- transpose + cast: (K,N) f32 -> (N,K) bf16 ----------------
__global__ __launch_bounds__(256) void k_transpose_cast(
    const float* __restrict__ S, u16* __restrict__ D, int K, int N, int ldd)
{
  __shared__ float t[32][33];
  int k0 = blockIdx.y*32, n0 = blockIdx.x*32;
  int tx = threadIdx.x, ty = threadIdx.y;   // 32 x 8
  #pragma unroll
  for (int i=0;i<4;++i){
    int k = k0 + ty + i*8, n = n0 + tx;
    if (k < K && n < N) t[ty+i*8][tx] = S[(size_t)k*N + n];
  }
  __syncthreads();
  #pragma unroll
  for (int i=0;i<4;++i){
    int n = n0 + ty + i*8, k = k0 + tx;
    if (n < N && k < K) D[(size_t)n*ldd + k] = f2b(t[tx][ty+i*8]);
  }
}

// ---------------- input projection: relu(x@W1+b1) -> bf16 ----------------
__global__ __launch_bounds__(256) void k_gemm1_relu(
    const float* __restrict__ X, const float* __restrict__ W1,
    const float* __restrict__ b1, u16* __restrict__ H0)
{
  __shared__ float As[64][73];
  __shared__ float Bs[72][64];
  int m0 = blockIdx.y*64, n0 = blockIdx.x*64;
  int tid = threadIdx.x;
  for (int idx=tid; idx<64*NIN; idx+=256){ int r=idx/NIN, k=idx-r*NIN; As[r][k] = X[(size_t)(m0+r)*NIN + k]; }
  for (int idx=tid; idx<NIN*64; idx+=256){ int k=idx>>6, n=idx&63; Bs[k][n] = W1[(size_t)k*HDIM + n0+n]; }
  __syncthreads();
  int tx = tid & 15, ty = tid >> 4;
  float acc[4][4] = {};
  for (int k=0;k<NIN;++k){
    float a[4], bv[4];
    #pragma unroll
    for (int i=0;i<4;++i) a[i]=As[ty*4+i][k];
    #pragma unroll
    for (int j=0;j<4;++j) bv[j]=Bs[k][tx*4+j];
    #pragma unroll
    for (int i=0;i<4;++i)
      #pragma unroll
      for (int j=0;j<4;++j) acc[i][j] += a[i]*bv[j];
  }
  #pragma unroll
  for (int i=0;i<4;++i){
    int row = m0 + ty*4 + i;
    #pragma unroll
    for (int j=0;j<4;++j){
      int col = n0 + tx*4 + j;
      float v = acc[i][j] + b1[col];
      H0[(size_t)row*HDIM + col] = f2b(v > 0.f ? v : 0.f);
    }
  }
}

// ---------------- LayerNorm (bf16 in -> bf16 out), one wave per row ----------------
template<int D>
__global__ __launch_bounds__(256) void k_ln(
    const u16* __restrict__ X, const float* __restrict__ g,
    const float* __restrict__ be, u16* __restrict__ Y)
{
  int wrow = (blockIdx.x*256 + threadIdx.x) >> 6;
  int lane = threadIdx.x & 63;
  constexpr int E = D/64;
  const u16* row = X + (size_t)wrow*D;
  float vals[E];
  float s=0.f, s2=0.f;
  #pragma unroll
  for (int i=0;i<E/4;++i){
    ushort4 u = *(const ushort4*)(row + i*256 + lane*4);
    float v0=b2f(u.x), v1=b2f(u.y), v2=b2f(u.z), v3=b2f(u.w);
    vals[i*4+0]=v0; vals[i*4+1]=v1; vals[i*4+2]=v2; vals[i*4+3]=v3;
    s  += v0+v1+v2+v3;
    s2 += v0*v0+v1*v1+v2*v2+v3*v3;
  }
  #pragma unroll
  for (int off=32; off; off>>=1){ s += __shfl_xor(s,off); s2 += __shfl_xor(s2,off); }
  float mean = s * (1.f/D);
  float var  = s2 * (1.f/D) - mean*mean;
  float rstd = rsqrtf(var + 1e-5f);
  u16* yr = Y + (size_t)wrow*D;
  #pragma unroll
  for (int i=0;i<E/4;++i){
    int col = i*256 + lane*4;
    float4 gg = *(const float4*)(g+col);
    float4 bb = *(const float4*)(be+col);
    ushort4 o;
    o.x = f2b((vals[i*4+0]-mean)*rstd*gg.x + bb.x);
    o.y = f2b((vals[i*4+1]-mean)*rstd*gg.y + bb.y);
    o.z = f2b((vals[i*4+2]-mean)*rstd*gg.z + bb.z);
    o.w = f2b((vals[i*4+3]-mean)*rstd*gg.w + bb.w);
    *(ushort4*)(yr + col) = o;
  }
}

// ======== 256x256 bf16 MFMA GEMM (R7/R9/R12 proven 134us): single barrier/tile,
// ds_read issues hoisted ahead of MFMA clusters, B frags double-buffered. =======
__global__ __launch_bounds__(512, 2) void k_gemm256(
    const u16* __restrict__ A, const u16* __restrict__ BT,
    u16* __restrict__ C, int K, int N)
{
  __shared__ u16 lds[65536];   // 128 KiB
  const int tid  = threadIdx.x;
  const int lane = tid & 63;
  const int wid  = tid >> 6;        // 0..7
  const int wm   = wid >> 2;        // 0..1
  const int wn   = wid & 3;         // 0..3

  // XCD-aware bijective swizzle (nwg % 8 == 0 for all launches)
  const int nbx = gridDim.x;
  const int nwg = nbx * gridDim.y;
  const int bid = blockIdx.y * nbx + blockIdx.x;
  const int cpx = nwg >> 3;
  const int swz = (bid & 7) * cpx + (bid >> 3);
  const int m0 = (swz / nbx) * 256;
  const int n0 = (swz % nbx) * 256;

  const int l3 = lane >> 3, l7 = lane & 7;
  const int kswz = (l7 ^ l3) * 8;   // pre-swizzled k-element offset for staging

  auto stageA = [&](int ts, int h, int db){
    const u16* base = A + (size_t)(m0 + h*128 + wid*8 + l3)*K + ts*64 + kswz;
    u16* dst = lds + db*32768 + h*8192 + wid*512;
    gload16(base,               dst);
    gload16(base + (size_t)64*K, dst + 4096);
  };
  auto stageB = [&](int ts, int db){
    const u16* base = BT + (size_t)(n0 + wid*8 + l3)*K + ts*64 + kswz;
    u16* dst = lds + db*32768 + 16384 + wid*512;
    gload16(base,                dst);
    gload16(base + (size_t) 64*K, dst + 4096);
    gload16(base + (size_t)128*K, dst + 8192);
    gload16(base + (size_t)192*K, dst + 12288);
  };
  auto rdfrag = [&](const u16* buf, int row, int ks)->bf16x8 {
    int byte = (row*128 + (ks*32 + ((lane>>4)*8))*2) ^ ((row&7)<<4);
    return __builtin_bit_cast(bf16x8, *(const s16x8*)((const char*)buf + byte));
  };

  f32x4 acc[8][4] = {};
  bf16x8 afr[2][2][2];    // [parity][mm][ks], static indexing
  bf16x8 bfr0[4][2], bfr1[4][2];
  const int nt = K >> 6;  // 8 or 16 (always even)

  // prologue: stage tile 0, drain, read B(0)->bfr0 and A0(0)->afr[0]
  stageA(0, 0, 0);
  stageA(0, 1, 0);
  stageB(0, 0);
  asm volatile("s_waitcnt vmcnt(0)" ::: "memory");
  __builtin_amdgcn_sched_barrier(0);
  __builtin_amdgcn_s_barrier();
  __builtin_amdgcn_sched_barrier(0);
  #pragma unroll
  for (int n=0;n<4;++n)
    #pragma unroll
    for (int ks=0;ks<2;++ks)
      bfr0[n][ks] = rdfrag(lds + 16384, wn*64 + n*16 + (lane&15), ks);
  #pragma unroll
  for (int mm=0;mm<2;++mm)
    #pragma unroll
    for (int ks=0;ks<2;++ks)
      afr[0][mm][ks] = rdfrag(lds, wm*128 + mm*16 + (lane&15), ks);

  auto tile = [&](int t, bf16x8 (&bcur)[4][2], bf16x8 (&bnxt)[4][2]){
    const u16* bufA  = lds + (t & 1)*32768;
    const int  tn    = (t+1 < nt) ? t+1 : t;   // tail: dummy re-stage keeps counts uniform
    const int  db    = (t+1) & 1;
    const u16* bufAn = lds + db*32768;
    const u16* bufBn = bufAn + 16384;

    // TOP: stage tile t+1 (8 loads)
    stageA(tn, 0, db);
    stageA(tn, 1, db);
    stageB(tn, db);

    // q0..q2: wait own frags (issued >=1 cluster ago) -> issue A(q+1) -> MFMA q
    #pragma unroll
    for (int q=0;q<3;++q){
      asm volatile("s_waitcnt lgkmcnt(0)" ::: "memory");
      __builtin_amdgcn_sched_barrier(0);
      #pragma unroll
      for (int mm=0;mm<2;++mm)
        #pragma unroll
        for (int ks=0;ks<2;++ks)
          afr[(q+1)&1][mm][ks] = rdfrag(bufA, wm*128 + ((q+1)*2+mm)*16 + (lane&15), ks);
      __builtin_amdgcn_sched_barrier(0);   // pin read-issue BEFORE the MFMA cluster
      __builtin_amdgcn_s_setprio(1);
      #pragma unroll
      for (int mm=0;mm<2;++mm)
        #pragma unroll
        for (int n=0;n<4;++n)
          #pragma unroll
          for (int ks=0;ks<2;++ks)
            acc[q*2+mm][n] = __builtin_amdgcn_mfma_f32_16x16x32_bf16(
                afr[q&1][mm][ks], bcur[n][ks], acc[q*2+mm][n], 0,0,0);
      __builtin_amdgcn_s_setprio(0);
    }

    // q3: drain loads (t+1 landed) + own A3 reads, ONE barrier, then issue
    // A0(t+1)+B(t+1) reads BEFORE the q3 MFMA cluster.
    asm volatile("s_waitcnt vmcnt(0) lgkmcnt(0)" ::: "memory");
    __builtin_amdgcn_sched_barrier(0);
    __builtin_amdgcn_s_barrier();
    __builtin_amdgcn_sched_barrier(0);
    #pragma unroll
    for (int mm=0;mm<2;++mm)
      #pragma unroll
      for (int ks=0;ks<2;++ks)
        afr[0][mm][ks] = rdfrag(bufAn, wm*128 + mm*16 + (lane&15), ks);
    #pragma unroll
    for (int n=0;n<4;++n)
      #pragma unroll
      for (int ks=0;ks<2;++ks)
        bnxt[n][ks] = rdfrag(bufBn, wn*64 + n*16 + (lane&15), ks);
    __builtin_amdgcn_sched_barrier(0);   // pin read-issue BEFORE the MFMA cluster
    __builtin_amdgcn_s_setprio(1);
    #pragma unroll
    for (int mm=0;mm<2;++mm)
      #pragma unroll
      for (int n=0;n<4;++n)
        #pragma unroll
        for (int ks=0;ks<2;++ks)
          acc[6+mm][n] = __builtin_amdgcn_mfma_f32_16x16x32_bf16(
              afr[1][mm][ks], bcur[n][ks], acc[6+mm][n], 0,0,0);
    __builtin_amdgcn_s_setprio(0);
  };

  for (int t = 0; t < nt; t += 2){
    tile(t,   bfr0, bfr1);
    tile(t+1, bfr1, bfr0);
  }

  // epilogue: C write (bf16)
  #pragma unroll
  for (int m=0;m<8;++m){
    int row = m0 + wm*128 + m*16 + ((lane>>4)<<2);
    #pragma unroll
    for (int n=0;n<4;++n){
      int col = n0 + wn*64 + n*16 + (lane&15);
      #pragma unroll
      for (int i=0;i<4;++i)
        C[(size_t)(row+i)*N + col] = f2b(acc[m][n][i]);
    }
  }
}

// ---------------- old 128x128 GEMM (kept for the small out-projection) ----------------
template<bool OUT_F32, bool HAS_BIAS>
__global__ __launch_bounds__(256) void k_gemm(
    const u16* __restrict__ A, const u16* __restrict__ BT,
    void* __restrict__ Cv, const float* __restrict__ bias,
    int K, int N, int ldc, int nbound)
{
  __shared__ u16 As[128*64];
  __shared__ u16 Bs[128*64];
  const int tid  = threadIdx.x;
  const int lane = tid & 63;
  const int wid  = tid >> 6;

  const int nbx = gridDim.x;
  const int nwg = nbx * gridDim.y;
  const int bid = blockIdx.y * nbx + blockIdx.x;
  const int cpx = nwg >> 3;
  const int swzb = (bid & 7) * cpx + (bid >> 3);
  const int bx = swzb % nbx, by = swzb / nbx;

  const int m0 = by * 128;
  const int n0 = bx * 128;
  const int wr = wid >> 1, wc = wid & 1;
  f32x4 acc[4][4] = {};

  const int srow = lane >> 3;
  const int skel = (lane & 7) * 8;

  for (int kt = 0; kt < K; kt += 64) {
    #pragma unroll
    for (int i=0;i<4;++i){
      int seg  = wid*4 + i;
      int arow = seg*8 + srow;
      gload16(A  + (size_t)(m0 + arow)*K + kt + skel, As + seg*512);
      gload16(BT + (size_t)(n0 + arow)*K + kt + skel, Bs + seg*512);
    }
    __syncthreads();
    #pragma unroll
    for (int ks=0; ks<2; ++ks){
      bf16x8 a[4], b[4];
      #pragma unroll
      for (int m=0;m<4;++m){
        int off = (wr*64 + m*16 + (lane&15))*64 + ks*32 + (lane>>4)*8;
        a[m] = __builtin_bit_cast(bf16x8, *(const s16x8*)(As + off));
      }
      #pragma unroll
      for (int n=0;n<4;++n){
        int off = (wc*64 + n*16 + (lane&15))*64 + ks*32 + (lane>>4)*8;
        b[n] = __builtin_bit_cast(bf16x8, *(const s16x8*)(Bs + off));
      }
      #pragma unroll
      for (int m=0;m<4;++m)
        #pragma unroll
        for (int n=0;n<4;++n)
          acc[m][n] = __builtin_amdgcn_mfma_f32_16x16x32_bf16(a[m], b[n], acc[m][n], 0,0,0);
    }
    __syncthreads();
  }

  #pragma unroll
  for (int m=0;m<4;++m){
    #pragma unroll
    for (int n=0;n<4;++n){
      int col = n0 + wc*64 + n*16 + (lane & 15);
      #pragma unroll
      for (int i=0;i<4;++i){
        int row = m0 + wr*64 + m*16 + ((lane>>4)<<2) + i;
        float v = acc[m][n][i];
        if (OUT_F32) {
          if (col < nbound){
            float bv = HAS_BIAS ? bias[col] : 0.f;
            ((float*)Cv)[(size_t)row*ldc + col] = v + bv;
          }
        } else {
          ((u16*)Cv)[(size_t)row*ldc + col] = f2b(v);
        }
      }
    }
  }
}

// ---------------- SRU scan v5: v4 arithmetic + DEEP ring (NS=8, D=6) ----------
// Residual ~60us/scan was memory latency beyond pipeline depth (D=3 ~= one L3
// round trip; only 12KB/wave in flight).  v5: 8 slots x 4KB = 32KB LDS, D=6
// iters = 48 steps lookahead, 24 loads (24KB) in flight per wave.
// vmcnt ledger (per-iter = 4 loads + 8 stores, in-order): wait at iter k for
// slot k+1 (issued iter k-5); ops after its last load = 8 + 4*12 + 4 = 60.
// Slot reuse: iter k writes slot (k+6)&7=(k-2)&7, consumed at iter k-3, fenced
// by that iter's lgkmcnt(0) (program order).  Tail dummies alias only
// already-consumed slots (j = k+D-8 < k).  Prologue drains vmcnt(0).
template<int KG>
__global__ __launch_bounds__(64) void k_scan(
    const u16* __restrict__ U, const u16* __restrict__ hwsrc,
    const float* __restrict__ v, const float* __restrict__ bb,
    u16* __restrict__ hout, float* __restrict__ states)
{
  constexpr int NS = 8;            // ring slots (4KB each) = 32 KB
  constexpr int D  = 6;            // prefetch distance in iters (48 steps)
  constexpr int NI = T_LEN/8;      // 64 iterations, 8 steps each
  __shared__ u16 ring[NS*2048];

  const int lane = threadIdx.x;
  const int bid  = blockIdx.x;
  const int hblk = bid & 7;
  const int b    = (bid >> 3) & 31;
  const int d    = bid >> 8;
  const int h    = hblk*64 + lane;
  const int RS   = 2*KG*HDIM;

  const int s2 = lane >> 5, p = (lane>>3)&3, c7 = lane&7;

  auto issue = [&](int k, int slot){
    #pragma unroll
    for (int half=0; half<4; ++half){
      int s = 8*k + 2*half + s2;
      int t = d ? (T_LEN-1-s) : s;
      int row = t*BATCH + b;
      const u16* g;
      if (KG == 4 || p < 3)
        g = U + (size_t)row*RS + (size_t)(d*KG + p)*HDIM + hblk*64 + c7*8;
      else
        g = hwsrc + (size_t)row*HDIM + hblk*64 + c7*8;
      gload16(g, &ring[slot*2048 + half*512]);
    }
  };

  const float vf  = v[(d*2+0)*HDIM + h];
  const float vr  = v[(d*2+1)*HDIM + h];
  const float bf_ = bb[(d*2+0)*HDIM + h];
  const float br_ = bb[(d*2+1)*HDIM + h];
  const float vfn = -vf, vrn = -vr;

  // per-slot register banks: x, af=-(f+bf), ar=-(r+br), w, w1=1-w
  auto ldslot = [&](int k, float (&xq)[8], float (&af)[8], float (&ar)[8],
                    float (&wq)[8], float (&w1)[8]){
    const u16* base = ring + (k & (NS-1))*2048;
    #pragma unroll
    for (int j=0;j<8;++j){
      xq[j] = b2f(base[j*256 + 0*64 + lane]);
      af[j] = -(b2f(base[j*256 + 1*64 + lane]) + bf_);
      ar[j] = -(b2f(base[j*256 + 2*64 + lane]) + br_);
      float w = b2f(base[j*256 + 3*64 + lane]);
      wq[j] = w; w1[j] = 1.f - w;
    }
  };

  for (int k=0;k<D;++k) issue(k, k);
  asm volatile("s_waitcnt vmcnt(0)" ::: "memory");
  __builtin_amdgcn_sched_barrier(0);

  float xA[8], fA[8], rA[8], wA[8], w1A[8];
  float xB[8], fB[8], rB[8], wB[8], w1B[8];
  ldslot(0, xA, fA, rA, wA, w1A);
  asm volatile("s_waitcnt lgkmcnt(0)" ::: "memory");
  __builtin_amdgcn_sched_barrier(0);

  float cst = 0.f;
  auto compute8 = [&](int k, float (&xq)[8], float (&af)[8], float (&ar)[8],
                      float (&wq)[8], float (&w1)[8]){
    #pragma unroll
    for (int j=0;j<8;++j){
      int s = 8*k + j;
      int t = d ? (T_LEN-1-s) : s;
      float f = __builtin_amdgcn_rcpf(1.f + __expf(fmaf(vfn, cst, af[j])));
      float r = __builtin_amdgcn_rcpf(1.f + __expf(fmaf(vrn, cst, ar[j])));
      cst = fmaf(f, cst - xq[j], xq[j]);                 // f*c + (1-f)*x
      float pE = __builtin_amdgcn_rcpf(1.f + __expf(cst * 2.f));
      float hv = fmaf(r, fmaf(-2.f, pE, w1[j]), wq[j]);  // r*tanh + (1-r)*w
      hout[(size_t)(t*BATCH + b)*(2*HDIM) + d*HDIM + h] =
          __builtin_bit_cast(u16, (__bf16)hv);           // native RNE cvt
    }
  };

  for (int k=0; k<NI; k+=2){
    {
      int kk = (k+D < NI) ? (k+D) : (NI-1);
      issue(kk, (k+D) & (NS-1));
      asm volatile("s_waitcnt vmcnt(60)" ::: "memory");   // slot k+1 loads retired
      __builtin_amdgcn_sched_barrier(0);
      ldslot(k+1, xB, fB, rB, wB, w1B);                   // ds_reads issue EARLY
      __builtin_amdgcn_sched_barrier(0);
      compute8(k, xA, fA, rA, wA, w1A);                   // hides ds_read latency
      asm volatile("s_waitcnt lgkmcnt(0)" ::: "memory");  // bank B ready
      __builtin_amdgcn_sched_barrier(0);
    }
    {
      int kk = (k+1+D < NI) ? (k+1+D) : (NI-1);
      issue(kk, (k+1+D) & (NS-1));
      asm volatile("s_waitcnt vmcnt(60)" ::: "memory");
      __builtin_amdgcn_sched_barrier(0);
      if (k+2 < NI) ldslot(k+2, xA, fA, rA, wA, w1A);
      __builtin_amdgcn_sched_barrier(0);
      compute8(k+1, xB, fB, rB, wB, w1B);
      asm volatile("s_waitcnt lgkmcnt(0)" ::: "memory");
      __builtin_amdgcn_sched_barrier(0);
    }
  }
  states[(size_t)b*(2*HDIM) + d*HDIM + h] = cst;
}

// ---------------- launch ----------------
extern "C" void kernel_launch(void* const* d_in, const int* in_sizes, int n_in,
                              void* d_out, int out_size, void* d_ws, size_t ws_size,
                              hipStream_t stream)
{
  const float* x   = (const float*)d_in[0];
  const float* W1  = (const float*)d_in[1];
  const float* b1  = (const float*)d_in[2];
  const float* W2  = (const float*)d_in[3];
  const float* b2  = (const float*)d_in[4];
  const float* W0  = (const float*)d_in[5];
  const float* v0  = (const float*)d_in[6];
  const float* bb0 = (const float*)d_in[7];
  const float* g0  = (const float*)d_in[8];
  const float* be0 = (const float*)d_in[9];
  const float* Ws  = (const float*)d_in[10];
  const float* vs  = (const float*)d_in[11];
  const float* bbs = (const float*)d_in[12];
  const float* gs  = (const float*)d_in[13];
  const float* bes = (const float*)d_in[14];
  (void)in_sizes; (void)n_in; (void)out_size; (void)ws_size;

  char* ws = (char*)d_ws;
  size_t off = 0;
  auto alloc = [&](size_t bytes)->void*{
    void* p = ws + off; off += (bytes + 255) & ~(size_t)255; return p;
  };
  u16* W0T  = (u16*)alloc((size_t)3072*512*2);
  u16* WsT  = (u16*)alloc((size_t)4*4096*1024*2);
  u16* W2T  = (u16*)alloc((size_t)128*1024*2);
  u16* h0   = (u16*)alloc((size_t)MROWS*512*2);
  u16* xn   = (u16*)alloc((size_t)MROWS*1024*2);
  u16* Ubuf = (u16*)alloc((size_t)MROWS*4096*2);
  u16* hbuf = (u16*)alloc((size_t)MROWS*1024*2);

  float* outp   = (float*)d_out;
  float* states = outp + (size_t)MROWS*NOUT;

  // --- weight prep (every call; deterministic) ---
  hipMemsetAsync(W2T, 0, (size_t)128*1024*2, stream);
  k_transpose_cast<<<dim3(3072/32, 512/32), dim3(32,8), 0, stream>>>(W0, W0T, 512, 3072, 512);
  for (int i=0;i<4;++i)
    k_transpose_cast<<<dim3(4096/32, 1024/32), dim3(32,8), 0, stream>>>(
        Ws + (size_t)i*1024*4096, WsT + (size_t)i*4096*1024, 1024, 4096, 1024);
  k_transpose_cast<<<dim3(3, 1024/32), dim3(32,8), 0, stream>>>(W2, W2T, 1024, NOUT, 1024);

  // --- input projection ---
  k_gemm1_relu<<<dim3(HDIM/64, MROWS/64), 256, 0, stream>>>(x, W1, b1, h0);

  // --- layer 0 (k=3, highway = layer input h0) ---
  k_ln<512><<<MROWS/4, 256, 0, stream>>>(h0, g0, be0, xn);
  k_gemm256<<<dim3(3072/256, MROWS/256), 512, 0, stream>>>(xn, W0T, Ubuf, 512, 3072);
  k_scan<3><<<512, 64, 0, stream>>>(Ubuf, h0, v0, bb0, hbuf, states);

  // --- layers 1..4 (k=4, highway = U[...,3]) ---
  for (int i=0;i<4;++i){
    k_ln<1024><<<MROWS/4, 256, 0, stream>>>(hbuf, gs + (size_t)i*1024, bes + (size_t)i*1024, xn);
    k_gemm256<<<dim3(4096/256, MROWS/256), 512, 0, stream>>>(
        xn, WsT + (size_t)i*4096*1024, Ubuf, 1024, 4096);
    k_scan<4><<<512, 64, 0, stream>>>(Ubuf, nullptr, vs + (size_t)i*2048, bbs + (size_t)i*2048,
                                      hbuf, states + (size_t)(i+1)*BATCH*1024);
  }

  // --- output projection (N padded to 128, bound 90, f32 out + bias) ---
  k_gemm<true,true><<<dim3(1, MROWS/128), 256, 0, stream>>>(
      hbuf, W2T, d_out, b2, 1024, 128, NOUT, NOUT);
}